// Round 4
// baseline (426.161 us; speedup 1.0000x reference)
//
#include <hip/hip_runtime.h>
#include <cstdint>
#include <cstddef>

// ---------------------------------------------------------------------------
// cross_attention: b=8, c=32, 252x252, ws=8 -> padded 256x256.
// tokens l=(i1,j1) in 32x32, features d'=(i0*256 + j0*32 + c) in 2048.
// Pipeline: norm (Q,K,V scales) -> pack_qk (bf16 Qh/Kh[l][d']) ->
//           pack_v (bf16 Vt[d'][l], RAW, no scale) ->
//           S = Qh Kh^T * 2048^-0.5 -> softmax rows -> Ot = (sv.*Vt) P^T
//           with sv folded into gemm2 epilogue + fused scatter/crop.
// ---------------------------------------------------------------------------

typedef __bf16 bf16x8 __attribute__((ext_vector_type(8)));
typedef float  f32x4  __attribute__((ext_vector_type(4)));

__device__ __forceinline__ unsigned int f2bf(float f) {
  unsigned int u = __builtin_bit_cast(unsigned int, f);
  u += 0x7FFFu + ((u >> 16) & 1u);   // round-to-nearest-even
  return u >> 16;
}
__device__ __forceinline__ float bf2f(unsigned short h) {
  return __builtin_bit_cast(float, (unsigned int)h << 16);
}

__device__ __forceinline__ void load_lds16(const void* g, void* l) {
  __builtin_amdgcn_global_load_lds(
      (const __attribute__((address_space(1))) void*)g,
      (__attribute__((address_space(3))) void*)l, 16, 0, 0);
}

// ---------------------------------------------------------------------------
// Kernel 1: column norms. Block = (t, b, c, g) with g = h-quarter (64 rows).
// Thread = one w column (w = tid, active w<252), loops 64 rows of coalesced
// scalar loads. Reflect padding by WEIGHTS: rows/cols 247..250 count 2x
// (col weight is thread-constant -> applied once at the end).
// scales[t][b][d'] = 1/max(norm,1e-12).
// ---------------------------------------------------------------------------
__global__ void norm_kernel(const float* __restrict__ q,
                            const float* __restrict__ k,
                            const float* __restrict__ v,
                            float* __restrict__ scales) {
  int bx = blockIdx.x;
  int t = bx >> 10;
  int b = (bx >> 7) & 7;
  int c = (bx >> 2) & 31;
  int g = bx & 3;              // h-quarter: rows [g*64, g*64+64), i0 = {2g,2g+1}
  const float* x = (t == 0) ? q : (t == 1) ? k : v;
  const float* base = x + ((size_t)b * 32 + c) * 63504;  // 252*252

  int tid = threadIdx.x;
  int w = tid;                               // column
  bool active = (w < 252);
  float cw = ((unsigned)(w - 247) <= 3u) ? 2.f : 1.f;

  float acc0 = 0.f, acc1 = 0.f;
  if (active) {
    int h0 = g * 64;
    int nrows = (g == 3) ? 60 : 64;          // rows >=252 are pure pad
    #pragma unroll 8
    for (int hh = 0; hh < 64; hh++) {
      if (hh < nrows) {
        int h = h0 + hh;
        float val = base[(size_t)h * 252 + w];
        float v2 = val * val;
        if ((unsigned)(h - 247) <= 3u) v2 *= 2.f;   // row mirror weight
        if (hh < 32) acc0 += v2; else acc1 += v2;
      }
    }
  }
  acc0 *= cw; acc1 *= cw;

  __shared__ float red[512];
  red[tid] = acc0;
  red[256 + tid] = acc1;
  __syncthreads();
  if (tid < 16) {              // tid = i0loc*8 + j0
    int i0loc = tid >> 3;
    int j0    = tid & 7;
    float s = 0.f;
    #pragma unroll
    for (int e = 0; e < 32; e++) s += red[i0loc * 256 + j0 * 32 + e];
    float sc = 1.0f / fmaxf(sqrtf(s), 1e-12f);
    int i0 = g * 2 + i0loc;
    scales[((size_t)(t * 8 + b)) * 2048 + i0 * 256 + j0 * 32 + c] = sc;
  }
}

// ---------------------------------------------------------------------------
// Kernel 2: pack Q,K to bf16 Qh/Kh[l][d']. Block = (t<2, b, i0, i1): one
// padded image row (32c x 256w) staged RAW in LDS (stride 257, window-rotated
// -> conflict-free), scales applied in the gather phase from 8 preloaded regs.
// ---------------------------------------------------------------------------
__global__ void pack_qk_kernel(const float* __restrict__ q,
                               const float* __restrict__ k,
                               const float* __restrict__ scales,
                               unsigned short* __restrict__ Qh,
                               unsigned short* __restrict__ Kh) {
  int bx = blockIdx.x;
  int t   = bx >> 11;          // 0..1
  int rem = bx & 2047;
  int b   = rem >> 8;
  int i0  = (rem >> 5) & 7;
  int i1  = rem & 31;
  const float* x = (t == 0) ? q : k;

  __shared__ float tf[32 * 257];   // 32.9 KB, raw values, rotated
  __shared__ float sclt[256];      // transposed: [c*8 + j0]

  int tid = threadIdx.x;
  sclt[(tid & 31) * 8 + (tid >> 5)] =
      scales[((size_t)(t * 8 + b)) * 2048 + i0 * 256 + tid];

  int h  = i0 * 32 + i1;
  int hs = (h < 252) ? h : 502 - h;
  const float* xb = x + (size_t)b * 32 * 63504 + (size_t)hs * 252;

  // ---- load phase: rotated scalar stores of RAW values ----
  #pragma unroll
  for (int r = 0; r < 8; r++) {
    int c     = r * 4 + (tid >> 6);
    int chunk = tid & 63;
    const float* src = xb + (size_t)c * 63504;
    int j0 = chunk >> 3, cq = chunk & 7;
    float4 vv;
    if (chunk < 63) {
      vv = *(const float4*)&src[chunk * 4];
    } else {  // cols 252..255 mirror to 250,249,248,247
      vv.x = src[250]; vv.y = src[249]; vv.z = src[248]; vv.w = src[247];
    }
    float* row = &tf[c * 257 + j0 * 32];
    int p = cq * 4 + j0;
    row[p & 31]       = vv.x;
    row[(p + 1) & 31] = vv.y;
    row[(p + 2) & 31] = vv.z;
    row[(p + 3) & 31] = vv.w;
  }
  __syncthreads();

  // ---- gather phase: scaled rotated reads, coalesced 16B global stores ----
  int p0  = (tid * 8) & 255;       // r-invariant
  int j0w = p0 >> 5;
  int c0  = p0 & 31;
  float scl_r[8];
  #pragma unroll
  for (int m = 0; m < 8; m++) scl_r[m] = sclt[(c0 + m) * 8 + j0w];

  unsigned short* X = ((t == 0) ? Qh : Kh) + (size_t)b * 1024 * 2048;
  #pragma unroll
  for (int r = 0; r < 4; r++) {
    int j1 = r * 8 + (tid >> 5);
    int rot = (j1 + j0w) & 31;
    unsigned int ov[4];
    #pragma unroll
    for (int m = 0; m < 4; m++) {
      float lo = tf[(c0 + 2 * m)     * 257 + j0w * 32 + rot] * scl_r[2 * m];
      float hi = tf[(c0 + 2 * m + 1) * 257 + j0w * 32 + rot] * scl_r[2 * m + 1];
      ov[m] = f2bf(lo) | (f2bf(hi) << 16);
    }
    int l = i1 * 32 + j1;
    uint4 o4; o4.x = ov[0]; o4.y = ov[1]; o4.z = ov[2]; o4.w = ov[3];
    *(uint4*)&X[(size_t)l * 2048 + i0 * 256 + p0] = o4;
  }
}

// ---------------------------------------------------------------------------
// Kernel 3: pack V to bf16 Vt[d'][l] — RAW (no scale; sv folded into gemm2),
// NO LDS: along l at fixed d' the source w is contiguous. Pure strided copy.
// Block = (b, i0, i1); thread = (j0g, c, j1c), 4 j0 iterations.
// ---------------------------------------------------------------------------
__global__ void pack_v_kernel(const float* __restrict__ v,
                              unsigned short* __restrict__ Vt) {
  int bx = blockIdx.x;
  int b  = bx >> 8;
  int i0 = (bx >> 5) & 7;
  int i1 = bx & 31;
  int h  = i0 * 32 + i1;
  int hs = (h < 252) ? h : 502 - h;
  const float* src = v + (size_t)b * 32 * 63504 + (size_t)hs * 252;
  unsigned short* dst = Vt + (size_t)b * 2048 * 1024
                           + (size_t)(i0 * 256) * 1024 + i1 * 32;

  int tid = threadIdx.x;
  int j1c = tid & 3;
  int c   = (tid >> 2) & 31;
  int j0g = tid >> 7;          // 0..1
  const float* s = src + (size_t)c * 63504;

  #pragma unroll
  for (int jj = 0; jj < 4; jj++) {
    int j0 = j0g * 4 + jj;
    int w0 = j0 * 32 + j1c * 8;
    float f0, f1, f2, f3, f4, f5, f6, f7;
    if (w0 + 8 <= 252) {
      float4 a = *(const float4*)&s[w0];
      float4 bq = *(const float4*)&s[w0 + 4];
      f0 = a.x; f1 = a.y; f2 = a.z; f3 = a.w;
      f4 = bq.x; f5 = bq.y; f6 = bq.z; f7 = bq.w;
    } else {  // w0==248: cols 248..255 -> 248,249,250,251,250,249,248,247
      float4 a = *(const float4*)&s[244];
      float4 bq = *(const float4*)&s[248];
      f0 = bq.x; f1 = bq.y; f2 = bq.z; f3 = bq.w;
      f4 = bq.z; f5 = bq.y; f6 = bq.x; f7 = a.w;
    }
    uint4 o;
    o.x = f2bf(f0) | (f2bf(f1) << 16);
    o.y = f2bf(f2) | (f2bf(f3) << 16);
    o.z = f2bf(f4) | (f2bf(f5) << 16);
    o.w = f2bf(f6) | (f2bf(f7) << 16);
    *(uint4*)&dst[(size_t)(j0 * 32 + c) * 1024 + j1c * 8] = o;
  }
}

// ---------------------------------------------------------------------------
// GEMM NT: C[M][N] = A[M][K] * B[N][K]^T, bf16 in, fp32 acc.
// 128x128 tile, 4 waves (2x2), each wave 4x4 of mfma_f32_16x16x32_bf16.
// Staging: global_load_lds width=16, XOR-swizzled source (conflict-free).
// MODE 0: store bf16 S * scale.  MODE 1: acc *= sv[row] (V col-norm folded),
// scatter fp32 to output with crop (row=d', col=l).
// ---------------------------------------------------------------------------
template <int MODE>
__global__ __launch_bounds__(256, 4)
void gemm_nt(const unsigned short* __restrict__ A,
             const unsigned short* __restrict__ B,
             int K, int Asb, int Bsb, void* __restrict__ Cout, float scale,
             const float* __restrict__ sv) {
  __shared__ unsigned short lA[128 * 64];  // 16 KB, no padding
  __shared__ unsigned short lB[128 * 64];
  __shared__ float svb[(MODE == 1) ? 128 : 1];

  const int tid  = threadIdx.x;
  const int lane = tid & 63;
  const int wave = tid >> 6;
  const int ln15 = lane & 15;
  const int q4   = lane >> 4;
  const int wm   = wave >> 1;
  const int wn   = wave & 1;
  const int m0   = blockIdx.y * 128;
  const int n0   = blockIdx.x * 128;
  const unsigned short* Ab = A + (size_t)blockIdx.z * Asb;
  const unsigned short* Bb = B + (size_t)blockIdx.z * Bsb;

  if (MODE == 1 && tid < 128)
    svb[tid] = sv[(size_t)blockIdx.z * 2048 + m0 + tid];

  const int srow = lane >> 3;       // row within 8-row staging group
  const int kcp  = lane & 7;        // physical 16B chunk (LDS dest = lane*16)
  const int kcl  = kcp ^ srow;      // logical chunk fetched (xor swizzle)

  f32x4 acc[4][4] = {};

  for (int k0 = 0; k0 < K; k0 += 64) {
    #pragma unroll
    for (int r = 0; r < 4; r++) {
      int rowg = wave * 32 + r * 8;                 // wave-uniform row base
      int row  = rowg + srow;
      load_lds16(&Ab[(size_t)(m0 + row) * K + k0 + kcl * 8], &lA[rowg * 64]);
      load_lds16(&Bb[(size_t)(n0 + row) * K + k0 + kcl * 8], &lB[rowg * 64]);
    }
    __syncthreads();
    #pragma unroll
    for (int kk = 0; kk < 2; kk++) {
      bf16x8 af[4], bfr[4];
      #pragma unroll
      for (int mt = 0; mt < 4; mt++) {
        int row = wm * 64 + mt * 16 + ln15;
        int pc  = (kk * 4 + q4) ^ (row & 7);
        af[mt] = *(const bf16x8*)&lA[row * 64 + pc * 8];
      }
      #pragma unroll
      for (int nt = 0; nt < 4; nt++) {
        int row = wn * 64 + nt * 16 + ln15;
        int pc  = (kk * 4 + q4) ^ (row & 7);
        bfr[nt] = *(const bf16x8*)&lB[row * 64 + pc * 8];
      }
      #pragma unroll
      for (int mt = 0; mt < 4; mt++)
        #pragma unroll
        for (int nt = 0; nt < 4; nt++)
          acc[mt][nt] = __builtin_amdgcn_mfma_f32_16x16x32_bf16(
              af[mt], bfr[nt], acc[mt][nt], 0, 0, 0);
    }
    __syncthreads();
  }

  if (MODE == 0) {
    unsigned short* Sb = (unsigned short*)Cout + (size_t)blockIdx.z * 1024 * 1024;
    #pragma unroll
    for (int mt = 0; mt < 4; mt++) {
      #pragma unroll
      for (int nt = 0; nt < 4; nt++) {
        int col = n0 + wn * 64 + nt * 16 + ln15;
        #pragma unroll
        for (int rg = 0; rg < 4; rg++) {
          int rowi = m0 + wm * 64 + mt * 16 + q4 * 4 + rg;
          Sb[(size_t)rowi * 1024 + col] = (unsigned short)f2bf(acc[mt][nt][rg] * scale);
        }
      }
    }
  } else {
    float* Ob = (float*)Cout;
    int bb = blockIdx.z;
    #pragma unroll
    for (int mt = 0; mt < 4; mt++) {
      #pragma unroll
      for (int nt = 0; nt < 4; nt++) {
        int l  = n0 + wn * 64 + nt * 16 + ln15;
        int i1 = l >> 5, j1 = l & 31;
        #pragma unroll
        for (int rg = 0; rg < 4; rg++) {
          int rloc = wm * 64 + mt * 16 + q4 * 4 + rg;
          int dp = m0 + rloc;          // d'
          int c  = dp & 31;
          int j0 = (dp >> 5) & 7;
          int i0 = dp >> 8;
          int h = i0 * 32 + i1;
          int w = j0 * 32 + j1;
          if (h < 252 && w < 252)
            Ob[(((size_t)bb * 32 + c) * 252 + h) * 252 + w] =
                acc[mt][nt][rg] * svb[rloc];
        }
      }
    }
  }
}

// ---------------------------------------------------------------------------
// Kernel 5: row softmax over S (bf16, in place -> P). Block per row (b,l).
// ---------------------------------------------------------------------------
__global__ void softmax_kernel(unsigned short* __restrict__ S) {
  unsigned short* row = S + (size_t)blockIdx.x * 1024;
  int tid  = threadIdx.x;
  int lane = tid & 63;
  int wid  = tid >> 6;

  uint2 u = *(const uint2*)&row[tid * 4];
  float x0 = bf2f((unsigned short)(u.x & 0xFFFF));
  float x1 = bf2f((unsigned short)(u.x >> 16));
  float x2 = bf2f((unsigned short)(u.y & 0xFFFF));
  float x3 = bf2f((unsigned short)(u.y >> 16));

  __shared__ float red[8];
  float mx = fmaxf(fmaxf(x0, x1), fmaxf(x2, x3));
  #pragma unroll
  for (int off = 32; off > 0; off >>= 1) mx = fmaxf(mx, __shfl_down(mx, off));
  if (lane == 0) red[wid] = mx;
  __syncthreads();
  if (tid == 0)
    red[4] = fmaxf(fmaxf(red[0], red[1]), fmaxf(red[2], red[3]));
  __syncthreads();
  float bm = red[4];

  float e0 = __expf(x0 - bm), e1 = __expf(x1 - bm);
  float e2 = __expf(x2 - bm), e3 = __expf(x3 - bm);
  float s = e0 + e1 + e2 + e3;
  #pragma unroll
  for (int off = 32; off > 0; off >>= 1) s += __shfl_down(s, off);
  if (lane == 0) red[wid] = s;
  __syncthreads();
  if (tid == 0) red[5] = 1.0f / (red[0] + red[1] + red[2] + red[3]);
  __syncthreads();
  float inv = red[5];

  unsigned int o0 = f2bf(e0 * inv) | (f2bf(e1 * inv) << 16);
  unsigned int o1 = f2bf(e2 * inv) | (f2bf(e3 * inv) << 16);
  uint2 o; o.x = o0; o.y = o1;
  *(uint2*)&row[tid * 4] = o;
}

// ---------------------------------------------------------------------------
extern "C" void kernel_launch(void* const* d_in, const int* in_sizes, int n_in,
                              void* d_out, int out_size, void* d_ws, size_t ws_size,
                              hipStream_t stream) {
  const float* q = (const float*)d_in[0];
  const float* k = (const float*)d_in[1];
  const float* v = (const float*)d_in[2];
  float* out = (float*)d_out;

  char* ws = (char*)d_ws;
  float* scales = (float*)ws;                                   // 196608 B
  unsigned short* Qh = (unsigned short*)(ws + 196608);          // 32 MB
  unsigned short* Kh = Qh + (size_t)8 * 1024 * 2048;            // 32 MB
  unsigned short* Vt = Kh + (size_t)8 * 1024 * 2048;            // 32 MB
  unsigned short* S  = Vt + (size_t)8 * 2048 * 1024;            // 16 MB

  const float SIM_SCALE = 0.02209708691207961f;  // 2048^-0.5
  const float* sv = scales + (size_t)2 * 8 * 2048;  // t=2 slice, [z][2048]

  norm_kernel<<<3072, 256, 0, stream>>>(q, k, v, scales);
  pack_qk_kernel<<<4096, 256, 0, stream>>>(q, k, scales, Qh, Kh);
  pack_v_kernel<<<2048, 256, 0, stream>>>(v, Vt);
  gemm_nt<0><<<dim3(8, 8, 8), 256, 0, stream>>>(
      Qh, Kh, 2048, 1024 * 2048, 1024 * 2048, (void*)S, SIM_SCALE, nullptr);
  softmax_kernel<<<8192, 256, 0, stream>>>(S);
  gemm_nt<1><<<dim3(8, 16, 8), 256, 0, stream>>>(
      Vt, S, 1024, 2048 * 1024, 1024 * 1024, (void*)out, 1.0f, sv);
}

// Round 5
// 399.862 us; speedup vs baseline: 1.0658x; 1.0658x over previous
//
#include <hip/hip_runtime.h>
#include <cstdint>
#include <cstddef>

// ---------------------------------------------------------------------------
// cross_attention: b=8, c=32, 252x252, ws=8 -> padded 256x256.
// tokens l=(i1,j1) in 32x32, features d'=(i0*256 + j0*32 + c) in 2048.
// Pipeline: norm (Q,K,V scales) -> pack_qk (bf16 Qh/Kh[l][d']) ->
//           pack_v (bf16 Vt[d'][l], RAW, no scale) ->
//           S = Qh Kh^T * 2048^-0.5 -> softmax rows -> Ot = (sv.*Vt) P^T
//           with sv folded into gemm2 epilogue + fused scatter/crop.
// ---------------------------------------------------------------------------

typedef __bf16 bf16x8 __attribute__((ext_vector_type(8)));
typedef float  f32x4  __attribute__((ext_vector_type(4)));

__device__ __forceinline__ unsigned int f2bf(float f) {
  unsigned int u = __builtin_bit_cast(unsigned int, f);
  u += 0x7FFFu + ((u >> 16) & 1u);   // round-to-nearest-even
  return u >> 16;
}
__device__ __forceinline__ float bf2f(unsigned short h) {
  return __builtin_bit_cast(float, (unsigned int)h << 16);
}

__device__ __forceinline__ void load_lds16(const void* g, void* l) {
  __builtin_amdgcn_global_load_lds(
      (const __attribute__((address_space(1))) void*)g,
      (__attribute__((address_space(3))) void*)l, 16, 0, 0);
}

// ---------------------------------------------------------------------------
// Kernel 1: column norms. Block = (t, b, c): one full 252x252 image.
// Thread = (i1b = tid>>6, chunk = tid&63): float4 column chunk, loops i0
// strips with 8 preloaded float4s each (branch-free bodies -> deep ILP).
// Reflect padding by WEIGHTS: rows/cols 247..250 count 2x, pads >=252 never
// loaded. scales[t][b][d'] = 1/max(norm,1e-12).
// NOTE (R4 post-mortem): scalar per-row loop with in-loop branches ran at
// 938 GB/s / 12 VGPRs. Preloaded float4 batches are the proven shape.
// ---------------------------------------------------------------------------
__global__ void norm_kernel(const float* __restrict__ q,
                            const float* __restrict__ k,
                            const float* __restrict__ v,
                            float* __restrict__ scales) {
  int bx = blockIdx.x;
  int t = bx >> 8;             // 0..2
  int b = (bx >> 5) & 7;
  int c = bx & 31;
  const float* x = (t == 0) ? q : (t == 1) ? k : v;
  const float* base = x + ((size_t)b * 32 + c) * 63504;  // 252*252

  int tid   = threadIdx.x;
  int chunk = tid & 63;        // 4-wide column chunk
  int i1b   = tid >> 6;        // 0..3

  float cw0 = 1.f, cw1 = 1.f, cw2 = 1.f, cw3 = 1.f;
  bool skipc = false;
  if (chunk == 61) cw3 = 2.f;                       // col 247
  else if (chunk == 62) { cw0 = cw1 = cw2 = 2.f; }  // cols 248..250
  else if (chunk == 63) skipc = true;               // cols 252..255 (pure pad)

  float acc[8];
  #pragma unroll
  for (int i = 0; i < 8; i++) acc[i] = 0.f;

  if (!skipc) {
    const float* colp = base + chunk * 4 + (size_t)i1b * 252;
    #pragma unroll
    for (int i0 = 0; i0 < 7; i0++) {
      float4 vv[8];
      #pragma unroll
      for (int r = 0; r < 8; r++)
        vv[r] = *(const float4*)&colp[(size_t)(i0 * 32 + r * 4) * 252];
      float s = 0.f;
      #pragma unroll
      for (int r = 0; r < 8; r++)
        s += cw0 * vv[r].x * vv[r].x + cw1 * vv[r].y * vv[r].y +
             cw2 * vv[r].z * vv[r].z + cw3 * vv[r].w * vv[r].w;
      acc[i0] = s;
    }
    {  // i0 == 7: rows 224..251 only (r*4+i1b < 28), mirror rows 247..250 x2
      float4 vv[7];
      #pragma unroll
      for (int r = 0; r < 7; r++)
        vv[r] = *(const float4*)&colp[(size_t)(224 + r * 4) * 252];
      float s = 0.f;
      #pragma unroll
      for (int r = 0; r < 7; r++) {
        int i1 = r * 4 + i1b;
        float rw = ((unsigned)(i1 - 23) <= 3u) ? 2.f : 1.f;  // h in 247..250
        s += rw * (cw0 * vv[r].x * vv[r].x + cw1 * vv[r].y * vv[r].y +
                   cw2 * vv[r].z * vv[r].z + cw3 * vv[r].w * vv[r].w);
      }
      acc[7] = s;
    }
  }

  __shared__ float red[256];
  float* dst = scales + ((size_t)(t * 8 + b)) * 2048;
  #pragma unroll
  for (int i0 = 0; i0 < 8; i0++) {
    red[tid] = acc[i0];
    __syncthreads();
    if (tid < 8) {  // tid = j0
      float s = 0.f;
      #pragma unroll
      for (int w = 0; w < 4; w++)
        #pragma unroll
        for (int e = 0; e < 8; e++) s += red[w * 64 + tid * 8 + e];
      dst[i0 * 256 + tid * 32 + c] = 1.0f / fmaxf(sqrtf(s), 1e-12f);
    }
    __syncthreads();
  }
}

// ---------------------------------------------------------------------------
// Kernel 2: pack Q,K to bf16 Qh/Kh[l][d']. Block = (t<2, b, i0, i1): one
// padded image row (32c x 256w) staged RAW in LDS (stride 257, window-rotated
// -> conflict-free), scales applied in the gather phase from 8 preloaded regs.
// ---------------------------------------------------------------------------
__global__ void pack_qk_kernel(const float* __restrict__ q,
                               const float* __restrict__ k,
                               const float* __restrict__ scales,
                               unsigned short* __restrict__ Qh,
                               unsigned short* __restrict__ Kh) {
  int bx = blockIdx.x;
  int t   = bx >> 11;          // 0..1
  int rem = bx & 2047;
  int b   = rem >> 8;
  int i0  = (rem >> 5) & 7;
  int i1  = rem & 31;
  const float* x = (t == 0) ? q : k;

  __shared__ float tf[32 * 257];   // 32.9 KB, raw values, rotated
  __shared__ float sclt[256];      // transposed: [c*8 + j0]

  int tid = threadIdx.x;
  sclt[(tid & 31) * 8 + (tid >> 5)] =
      scales[((size_t)(t * 8 + b)) * 2048 + i0 * 256 + tid];

  int h  = i0 * 32 + i1;
  int hs = (h < 252) ? h : 502 - h;
  const float* xb = x + (size_t)b * 32 * 63504 + (size_t)hs * 252;

  // ---- load phase: rotated scalar stores of RAW values ----
  #pragma unroll
  for (int r = 0; r < 8; r++) {
    int c     = r * 4 + (tid >> 6);
    int chunk = tid & 63;
    const float* src = xb + (size_t)c * 63504;
    int j0 = chunk >> 3, cq = chunk & 7;
    float4 vv;
    if (chunk < 63) {
      vv = *(const float4*)&src[chunk * 4];
    } else {  // cols 252..255 mirror to 250,249,248,247
      vv.x = src[250]; vv.y = src[249]; vv.z = src[248]; vv.w = src[247];
    }
    float* row = &tf[c * 257 + j0 * 32];
    int p = cq * 4 + j0;
    row[p & 31]       = vv.x;
    row[(p + 1) & 31] = vv.y;
    row[(p + 2) & 31] = vv.z;
    row[(p + 3) & 31] = vv.w;
  }
  __syncthreads();

  // ---- gather phase: scaled rotated reads, coalesced 16B global stores ----
  int p0  = (tid * 8) & 255;       // r-invariant
  int j0w = p0 >> 5;
  int c0  = p0 & 31;
  float scl_r[8];
  #pragma unroll
  for (int m = 0; m < 8; m++) scl_r[m] = sclt[(c0 + m) * 8 + j0w];

  unsigned short* X = ((t == 0) ? Qh : Kh) + (size_t)b * 1024 * 2048;
  #pragma unroll
  for (int r = 0; r < 4; r++) {
    int j1 = r * 8 + (tid >> 5);
    int rot = (j1 + j0w) & 31;
    unsigned int ov[4];
    #pragma unroll
    for (int m = 0; m < 4; m++) {
      float lo = tf[(c0 + 2 * m)     * 257 + j0w * 32 + rot] * scl_r[2 * m];
      float hi = tf[(c0 + 2 * m + 1) * 257 + j0w * 32 + rot] * scl_r[2 * m + 1];
      ov[m] = f2bf(lo) | (f2bf(hi) << 16);
    }
    int l = i1 * 32 + j1;
    uint4 o4; o4.x = ov[0]; o4.y = ov[1]; o4.z = ov[2]; o4.w = ov[3];
    *(uint4*)&X[(size_t)l * 2048 + i0 * 256 + p0] = o4;
  }
}

// ---------------------------------------------------------------------------
// Kernel 3: pack V to bf16 Vt[d'][l] — RAW (no scale; sv folded into gemm2),
// NO LDS: along l at fixed d' the source w is contiguous. Pure strided copy.
// Block = (b, i0, i1); thread = (j0g, c, j1c), 4 j0 iterations.
// ---------------------------------------------------------------------------
__global__ void pack_v_kernel(const float* __restrict__ v,
                              unsigned short* __restrict__ Vt) {
  int bx = blockIdx.x;
  int b  = bx >> 8;
  int i0 = (bx >> 5) & 7;
  int i1 = bx & 31;
  int h  = i0 * 32 + i1;
  int hs = (h < 252) ? h : 502 - h;
  const float* src = v + (size_t)b * 32 * 63504 + (size_t)hs * 252;
  unsigned short* dst = Vt + (size_t)b * 2048 * 1024
                           + (size_t)(i0 * 256) * 1024 + i1 * 32;

  int tid = threadIdx.x;
  int j1c = tid & 3;
  int c   = (tid >> 2) & 31;
  int j0g = tid >> 7;          // 0..1
  const float* s = src + (size_t)c * 63504;

  #pragma unroll
  for (int jj = 0; jj < 4; jj++) {
    int j0 = j0g * 4 + jj;
    int w0 = j0 * 32 + j1c * 8;
    float f0, f1, f2, f3, f4, f5, f6, f7;
    if (w0 + 8 <= 252) {
      float4 a = *(const float4*)&s[w0];
      float4 bq = *(const float4*)&s[w0 + 4];
      f0 = a.x; f1 = a.y; f2 = a.z; f3 = a.w;
      f4 = bq.x; f5 = bq.y; f6 = bq.z; f7 = bq.w;
    } else {  // w0==248: cols 248..255 -> 248,249,250,251,250,249,248,247
      float4 a = *(const float4*)&s[244];
      float4 bq = *(const float4*)&s[248];
      f0 = bq.x; f1 = bq.y; f2 = bq.z; f3 = bq.w;
      f4 = bq.z; f5 = bq.y; f6 = bq.x; f7 = a.w;
    }
    uint4 o;
    o.x = f2bf(f0) | (f2bf(f1) << 16);
    o.y = f2bf(f2) | (f2bf(f3) << 16);
    o.z = f2bf(f4) | (f2bf(f5) << 16);
    o.w = f2bf(f6) | (f2bf(f7) << 16);
    *(uint4*)&dst[(size_t)(j0 * 32 + c) * 1024 + j1c * 8] = o;
  }
}

// ---------------------------------------------------------------------------
// GEMM NT: C[M][N] = A[M][K] * B[N][K]^T, bf16 in, fp32 acc.
// 128x128 tile, 4 waves (2x2), each wave 4x4 of mfma_f32_16x16x32_bf16.
// Staging: global_load_lds width=16, XOR-swizzled source (conflict-free).
// MODE 0: store bf16 S * scale.  MODE 1: acc *= sv[row] (V col-norm folded),
// scatter fp32 to output with crop (row=d', col=l).
// ---------------------------------------------------------------------------
template <int MODE>
__global__ __launch_bounds__(256, 4)
void gemm_nt(const unsigned short* __restrict__ A,
             const unsigned short* __restrict__ B,
             int K, int Asb, int Bsb, void* __restrict__ Cout, float scale,
             const float* __restrict__ sv) {
  __shared__ unsigned short lA[128 * 64];  // 16 KB, no padding
  __shared__ unsigned short lB[128 * 64];
  __shared__ float svb[(MODE == 1) ? 128 : 1];

  const int tid  = threadIdx.x;
  const int lane = tid & 63;
  const int wave = tid >> 6;
  const int ln15 = lane & 15;
  const int q4   = lane >> 4;
  const int wm   = wave >> 1;
  const int wn   = wave & 1;
  const int m0   = blockIdx.y * 128;
  const int n0   = blockIdx.x * 128;
  const unsigned short* Ab = A + (size_t)blockIdx.z * Asb;
  const unsigned short* Bb = B + (size_t)blockIdx.z * Bsb;

  if (MODE == 1 && tid < 128)
    svb[tid] = sv[(size_t)blockIdx.z * 2048 + m0 + tid];

  const int srow = lane >> 3;       // row within 8-row staging group
  const int kcp  = lane & 7;        // physical 16B chunk (LDS dest = lane*16)
  const int kcl  = kcp ^ srow;      // logical chunk fetched (xor swizzle)

  f32x4 acc[4][4] = {};

  for (int k0 = 0; k0 < K; k0 += 64) {
    #pragma unroll
    for (int r = 0; r < 4; r++) {
      int rowg = wave * 32 + r * 8;                 // wave-uniform row base
      int row  = rowg + srow;
      load_lds16(&Ab[(size_t)(m0 + row) * K + k0 + kcl * 8], &lA[rowg * 64]);
      load_lds16(&Bb[(size_t)(n0 + row) * K + k0 + kcl * 8], &lB[rowg * 64]);
    }
    __syncthreads();
    #pragma unroll
    for (int kk = 0; kk < 2; kk++) {
      bf16x8 af[4], bfr[4];
      #pragma unroll
      for (int mt = 0; mt < 4; mt++) {
        int row = wm * 64 + mt * 16 + ln15;
        int pc  = (kk * 4 + q4) ^ (row & 7);
        af[mt] = *(const bf16x8*)&lA[row * 64 + pc * 8];
      }
      #pragma unroll
      for (int nt = 0; nt < 4; nt++) {
        int row = wn * 64 + nt * 16 + ln15;
        int pc  = (kk * 4 + q4) ^ (row & 7);
        bfr[nt] = *(const bf16x8*)&lB[row * 64 + pc * 8];
      }
      #pragma unroll
      for (int mt = 0; mt < 4; mt++)
        #pragma unroll
        for (int nt = 0; nt < 4; nt++)
          acc[mt][nt] = __builtin_amdgcn_mfma_f32_16x16x32_bf16(
              af[mt], bfr[nt], acc[mt][nt], 0, 0, 0);
    }
    __syncthreads();
  }

  if (MODE == 0) {
    unsigned short* Sb = (unsigned short*)Cout + (size_t)blockIdx.z * 1024 * 1024;
    #pragma unroll
    for (int mt = 0; mt < 4; mt++) {
      #pragma unroll
      for (int nt = 0; nt < 4; nt++) {
        int col = n0 + wn * 64 + nt * 16 + ln15;
        #pragma unroll
        for (int rg = 0; rg < 4; rg++) {
          int rowi = m0 + wm * 64 + mt * 16 + q4 * 4 + rg;
          Sb[(size_t)rowi * 1024 + col] = (unsigned short)f2bf(acc[mt][nt][rg] * scale);
        }
      }
    }
  } else {
    float* Ob = (float*)Cout;
    int bb = blockIdx.z;
    #pragma unroll
    for (int mt = 0; mt < 4; mt++) {
      #pragma unroll
      for (int nt = 0; nt < 4; nt++) {
        int l  = n0 + wn * 64 + nt * 16 + ln15;
        int i1 = l >> 5, j1 = l & 31;
        #pragma unroll
        for (int rg = 0; rg < 4; rg++) {
          int rloc = wm * 64 + mt * 16 + q4 * 4 + rg;
          int dp = m0 + rloc;          // d'
          int c  = dp & 31;
          int j0 = (dp >> 5) & 7;
          int i0 = dp >> 8;
          int h = i0 * 32 + i1;
          int w = j0 * 32 + j1;
          if (h < 252 && w < 252)
            Ob[(((size_t)bb * 32 + c) * 252 + h) * 252 + w] =
                acc[mt][nt][rg] * svb[rloc];
        }
      }
    }
  }
}

// ---------------------------------------------------------------------------
// Kernel 5: row softmax over S (bf16, in place -> P). Block per row (b,l).
// ---------------------------------------------------------------------------
__global__ void softmax_kernel(unsigned short* __restrict__ S) {
  unsigned short* row = S + (size_t)blockIdx.x * 1024;
  int tid  = threadIdx.x;
  int lane = tid & 63;
  int wid  = tid >> 6;

  uint2 u = *(const uint2*)&row[tid * 4];
  float x0 = bf2f((unsigned short)(u.x & 0xFFFF));
  float x1 = bf2f((unsigned short)(u.x >> 16));
  float x2 = bf2f((unsigned short)(u.y & 0xFFFF));
  float x3 = bf2f((unsigned short)(u.y >> 16));

  __shared__ float red[8];
  float mx = fmaxf(fmaxf(x0, x1), fmaxf(x2, x3));
  #pragma unroll
  for (int off = 32; off > 0; off >>= 1) mx = fmaxf(mx, __shfl_down(mx, off));
  if (lane == 0) red[wid] = mx;
  __syncthreads();
  if (tid == 0)
    red[4] = fmaxf(fmaxf(red[0], red[1]), fmaxf(red[2], red[3]));
  __syncthreads();
  float bm = red[4];

  float e0 = __expf(x0 - bm), e1 = __expf(x1 - bm);
  float e2 = __expf(x2 - bm), e3 = __expf(x3 - bm);
  float s = e0 + e1 + e2 + e3;
  #pragma unroll
  for (int off = 32; off > 0; off >>= 1) s += __shfl_down(s, off);
  if (lane == 0) red[wid] = s;
  __syncthreads();
  if (tid == 0) red[5] = 1.0f / (red[0] + red[1] + red[2] + red[3]);
  __syncthreads();
  float inv = red[5];

  unsigned int o0 = f2bf(e0 * inv) | (f2bf(e1 * inv) << 16);
  unsigned int o1 = f2bf(e2 * inv) | (f2bf(e3 * inv) << 16);
  uint2 o; o.x = o0; o.y = o1;
  *(uint2*)&row[tid * 4] = o;
}

// ---------------------------------------------------------------------------
extern "C" void kernel_launch(void* const* d_in, const int* in_sizes, int n_in,
                              void* d_out, int out_size, void* d_ws, size_t ws_size,
                              hipStream_t stream) {
  const float* q = (const float*)d_in[0];
  const float* k = (const float*)d_in[1];
  const float* v = (const float*)d_in[2];
  float* out = (float*)d_out;

  char* ws = (char*)d_ws;
  float* scales = (float*)ws;                                   // 196608 B
  unsigned short* Qh = (unsigned short*)(ws + 196608);          // 32 MB
  unsigned short* Kh = Qh + (size_t)8 * 1024 * 2048;            // 32 MB
  unsigned short* Vt = Kh + (size_t)8 * 1024 * 2048;            // 32 MB
  unsigned short* S  = Vt + (size_t)8 * 2048 * 1024;            // 16 MB

  const float SIM_SCALE = 0.02209708691207961f;  // 2048^-0.5
  const float* sv = scales + (size_t)2 * 8 * 2048;  // t=2 slice, [z][2048]

  norm_kernel<<<768, 256, 0, stream>>>(q, k, v, scales);
  pack_qk_kernel<<<4096, 256, 0, stream>>>(q, k, scales, Qh, Kh);
  pack_v_kernel<<<2048, 256, 0, stream>>>(v, Vt);
  gemm_nt<0><<<dim3(8, 8, 8), 256, 0, stream>>>(
      Qh, Kh, 2048, 1024 * 2048, 1024 * 2048, (void*)S, SIM_SCALE, nullptr);
  softmax_kernel<<<8192, 256, 0, stream>>>(S);
  gemm_nt<1><<<dim3(8, 16, 8), 256, 0, stream>>>(
      Vt, S, 1024, 2048 * 1024, 1024 * 1024, (void*)out, 1.0f, sv);
}

// Round 6
// 376.654 us; speedup vs baseline: 1.1314x; 1.0616x over previous
//
#include <hip/hip_runtime.h>
#include <cstdint>
#include <cstddef>

// ---------------------------------------------------------------------------
// cross_attention: b=8, c=32, 252x252, ws=8 -> padded 256x256.
// tokens l=(i1,j1) in 32x32, features d'=(i0*256 + j0*32 + c) in 2048.
// Pipeline (R6): pack_qk_fused (norms computed in-block; raw bf16 pack +
//   in-place scale)  ->  pack_v (raw bf16 Vt)  ->  sv from Vt (bf16)  ->
//   S = Qh Kh^T * 2048^-0.5 -> softmax -> Ot = (sv.*Vt) P^T fused scatter.
// norm_kernel eliminated (-195 MB HBM): streaming kernels cap ~2.6 TB/s on
// this platform regardless of shape (R2 vs R5 evidence), so bytes are the
// only lever.
// ---------------------------------------------------------------------------

typedef __bf16 bf16x8 __attribute__((ext_vector_type(8)));
typedef float  f32x4  __attribute__((ext_vector_type(4)));

__device__ __forceinline__ unsigned int f2bf(float f) {
  unsigned int u = __builtin_bit_cast(unsigned int, f);
  u += 0x7FFFu + ((u >> 16) & 1u);   // round-to-nearest-even
  return u >> 16;
}
__device__ __forceinline__ float bf2f(unsigned int h) {
  return __builtin_bit_cast(float, h << 16);
}

__device__ __forceinline__ void load_lds16(const void* g, void* l) {
  __builtin_amdgcn_global_load_lds(
      (const __attribute__((address_space(1))) void*)g,
      (__attribute__((address_space(3))) void*)l, 16, 0, 0);
}

// ---------------------------------------------------------------------------
// Kernel 1: fused norm+pack for Q,K. Block = (t, b, i0, j0g): owns the
// 32c x 32h x 64w strip (w in [j0g*64, j0g*64+64)) = windows (i0, j0g*2+{0,1}).
// Loop i1: stage raw fp32 row-slice in tf[32][65] (<=2-way banks), gather raw
// bf16 uint4 -> Qh/Kh (128B contiguous, lines fully owned), accumulating
// weighted squares for the 64 (c,j0l) window norms. Then reduce -> scales,
// and phase C rescales the block's own 1024x64 output region in place
// (L2-hot round trip). Reflect pad by weights (247..250 x2, >=252 -> 0).
// ---------------------------------------------------------------------------
__global__ __launch_bounds__(256)
void pack_qk_fused(const float* __restrict__ q, const float* __restrict__ k,
                   unsigned short* __restrict__ Qh,
                   unsigned short* __restrict__ Kh) {
  int bx  = blockIdx.x;          // grid 512
  int t   = bx >> 8;             // 0..1
  int b   = (bx >> 5) & 7;
  int i0  = (bx >> 2) & 7;
  int j0g = bx & 3;
  const float* xb = (t ? k : q) + (size_t)b * 32 * 63504;

  __shared__ float tf[32 * 65];    // [c][pos 0..63], stride 65 -> bank = c+pos
  __shared__ float red[512];
  __shared__ float sclt[64];       // [c*2 + j0l]

  int tid = threadIdx.x;
  int ch  = tid & 15;              // 16B chunk within 64-w slice
  int c2  = tid >> 4;              // c = c2, c2+16

  int wbase = j0g * 64 + ch * 4;
  float we[4];
  #pragma unroll
  for (int e = 0; e < 4; e++) {
    int w = wbase + e;
    we[e] = (w >= 252) ? 0.f : (((unsigned)(w - 247) <= 3u) ? 2.f : 1.f);
  }
  bool tail = (wbase == 252);      // only j0g==3, ch==15

  float pa = 0.f, pb = 0.f;        // window sums for c2 / c2+16 (j0l fixed)
  unsigned short* X = (t ? Kh : Qh) + (size_t)b * 1024 * 2048;

  int gsub = tid & 7;              // gather: d' octet within 64
  int gj1  = tid >> 3;
  int gjl  = gsub >> 2;
  int gc0  = (gsub & 3) * 8;

  for (int i1 = 0; i1 < 32; i1++) {
    int h  = i0 * 32 + i1;
    int hs = (h < 252) ? h : 502 - h;
    float rw = (h >= 252) ? 0.f : (((unsigned)(h - 247) <= 3u) ? 2.f : 1.f);
    const float* rowp = xb + (size_t)hs * 252;

    #pragma unroll
    for (int it = 0; it < 2; it++) {
      int c = c2 + it * 16;
      const float* src = rowp + (size_t)c * 63504;
      float4 vv;
      if (!tail) {
        vv = *(const float4*)&src[wbase];
      } else {  // w 252..255 mirror to 250,249,248,247
        vv.x = src[250]; vv.y = src[249]; vv.z = src[248]; vv.w = src[247];
      }
      float s = rw * (we[0] * vv.x * vv.x + we[1] * vv.y * vv.y +
                      we[2] * vv.z * vv.z + we[3] * vv.w * vv.w);
      if (it == 0) pa += s; else pb += s;
      float* dst = &tf[c * 65 + ch * 4];
      dst[0] = vv.x; dst[1] = vv.y; dst[2] = vv.z; dst[3] = vv.w;
    }
    __syncthreads();
    {
      int pos = gjl * 32 + gj1;
      unsigned int ov[4];
      #pragma unroll
      for (int m = 0; m < 4; m++) {
        unsigned int lo = f2bf(tf[(gc0 + 2 * m)     * 65 + pos]);
        unsigned int hi = f2bf(tf[(gc0 + 2 * m + 1) * 65 + pos]);
        ov[m] = lo | (hi << 16);
      }
      int l = i1 * 32 + gj1;
      uint4 o4; o4.x = ov[0]; o4.y = ov[1]; o4.z = ov[2]; o4.w = ov[3];
      *(uint4*)&X[(size_t)l * 2048 + i0 * 256 + j0g * 64 + gsub * 8] = o4;
    }
    __syncthreads();
  }

  // reduce partials -> 64 scales
  red[tid] = pa; red[256 + tid] = pb;
  __syncthreads();
  if (tid < 64) {
    int c = tid & 31, jl = tid >> 5;
    int base = (c & 15) * 16 + jl * 8 + ((c >= 16) ? 256 : 0);
    float s = 0.f;
    #pragma unroll
    for (int u = 0; u < 8; u++) s += red[base + u];
    sclt[c * 2 + jl] = 1.f / fmaxf(sqrtf(s), 1e-12f);
  }
  __syncthreads();

  // phase C: in-place scale of the block's 1024 x 64 d' region (L2-hot)
  {
    float sc[8];
    #pragma unroll
    for (int m = 0; m < 8; m++) sc[m] = sclt[(gc0 + m) * 2 + gjl];
    unsigned short* basep = &X[i0 * 256 + j0g * 64 + gsub * 8];
    int lb = tid >> 3;
    #pragma unroll 4
    for (int it = 0; it < 32; it++) {
      size_t off = (size_t)(it * 32 + lb) * 2048;
      uint4 u = *(uint4*)&basep[off];
      uint4 o;
      o.x = f2bf(bf2f(u.x & 0xFFFF) * sc[0]) | (f2bf(bf2f(u.x >> 16) * sc[1]) << 16);
      o.y = f2bf(bf2f(u.y & 0xFFFF) * sc[2]) | (f2bf(bf2f(u.y >> 16) * sc[3]) << 16);
      o.z = f2bf(bf2f(u.z & 0xFFFF) * sc[4]) | (f2bf(bf2f(u.z >> 16) * sc[5]) << 16);
      o.w = f2bf(bf2f(u.w & 0xFFFF) * sc[6]) | (f2bf(bf2f(u.w >> 16) * sc[7]) << 16);
      *(uint4*)&basep[off] = o;
    }
  }
}

// ---------------------------------------------------------------------------
// Kernel 2: pack V to bf16 Vt[d'][l] — RAW (sv folded into gemm2), no LDS.
// ---------------------------------------------------------------------------
__global__ void pack_v_kernel(const float* __restrict__ v,
                              unsigned short* __restrict__ Vt) {
  int bx = blockIdx.x;
  int b  = bx >> 8;
  int i0 = (bx >> 5) & 7;
  int i1 = bx & 31;
  int h  = i0 * 32 + i1;
  int hs = (h < 252) ? h : 502 - h;
  const float* src = v + (size_t)b * 32 * 63504 + (size_t)hs * 252;
  unsigned short* dst = Vt + (size_t)b * 2048 * 1024
                           + (size_t)(i0 * 256) * 1024 + i1 * 32;

  int tid = threadIdx.x;
  int j1c = tid & 3;
  int c   = (tid >> 2) & 31;
  int j0g = tid >> 7;          // 0..1
  const float* s = src + (size_t)c * 63504;

  #pragma unroll
  for (int jj = 0; jj < 4; jj++) {
    int j0 = j0g * 4 + jj;
    int w0 = j0 * 32 + j1c * 8;
    float f0, f1, f2, f3, f4, f5, f6, f7;
    if (w0 + 8 <= 252) {
      float4 a = *(const float4*)&s[w0];
      float4 bq = *(const float4*)&s[w0 + 4];
      f0 = a.x; f1 = a.y; f2 = a.z; f3 = a.w;
      f4 = bq.x; f5 = bq.y; f6 = bq.z; f7 = bq.w;
    } else {  // w0==248: cols 248..255 -> 248,249,250,251,250,249,248,247
      float4 a = *(const float4*)&s[244];
      float4 bq = *(const float4*)&s[248];
      f0 = bq.x; f1 = bq.y; f2 = bq.z; f3 = bq.w;
      f4 = bq.z; f5 = bq.y; f6 = bq.x; f7 = a.w;
    }
    uint4 o;
    o.x = f2bf(f0) | (f2bf(f1) << 16);
    o.y = f2bf(f2) | (f2bf(f3) << 16);
    o.z = f2bf(f4) | (f2bf(f5) << 16);
    o.w = f2bf(f6) | (f2bf(f7) << 16);
    *(uint4*)&dst[(size_t)(j0 * 32 + c) * 1024 + j1c * 8] = o;
  }
}

// ---------------------------------------------------------------------------
// Kernel 3: sv[d'] = 1/max(||Vt row||,1e-12) from bf16 Vt (L2/LLC-hot).
// Block = (b, 64-row group); 4 threads per row, interleaved 16B chunks.
// ---------------------------------------------------------------------------
__global__ void sv_kernel(const unsigned short* __restrict__ Vt,
                          float* __restrict__ sv) {
  int bx = blockIdx.x;          // 256
  int b  = bx >> 5;
  int dg = bx & 31;
  int tid = threadIdx.x;
  int r  = tid >> 2;            // local row 0..63
  int qd = tid & 3;
  const unsigned short* row =
      Vt + (size_t)b * 2048 * 1024 + (size_t)(dg * 64 + r) * 1024;
  float s = 0.f;
  #pragma unroll 8
  for (int it = 0; it < 32; it++) {
    uint4 u = *(const uint4*)&row[it * 32 + qd * 8];
    float a0 = bf2f(u.x & 0xFFFF), a1 = bf2f(u.x >> 16);
    float a2 = bf2f(u.y & 0xFFFF), a3 = bf2f(u.y >> 16);
    float a4 = bf2f(u.z & 0xFFFF), a5 = bf2f(u.z >> 16);
    float a6 = bf2f(u.w & 0xFFFF), a7 = bf2f(u.w >> 16);
    s += a0*a0 + a1*a1 + a2*a2 + a3*a3 + a4*a4 + a5*a5 + a6*a6 + a7*a7;
  }
  s += __shfl_down(s, 2, 4);
  s += __shfl_down(s, 1, 4);
  if (qd == 0)
    sv[(size_t)b * 2048 + dg * 64 + r] = 1.f / fmaxf(sqrtf(s), 1e-12f);
}

// ---------------------------------------------------------------------------
// GEMM NT: C[M][N] = A[M][K] * B[N][K]^T, bf16 in, fp32 acc.
// 1D grid, decode: b = flat&7 (XCD affinity), m = (flat>>3)>>3, n = flat&7
// of the remainder -> successive same-XCD blocks reuse the A-tile in L2.
// MODE 0: store bf16 S * scale.  MODE 1: acc *= sv[row], scatter fp32 + crop.
// ---------------------------------------------------------------------------
template <int MODE>
__global__ __launch_bounds__(256, 4)
void gemm_nt(const unsigned short* __restrict__ A,
             const unsigned short* __restrict__ B,
             int K, int Asb, int Bsb, void* __restrict__ Cout, float scale,
             const float* __restrict__ sv) {
  __shared__ unsigned short lA[128 * 64];
  __shared__ unsigned short lB[128 * 64];
  __shared__ float svb[(MODE == 1) ? 128 : 1];

  const int flat = blockIdx.x;
  const int zz   = flat & 7;
  const int rr   = flat >> 3;
  const int my   = rr >> 3;
  const int nx   = rr & 7;

  const int tid  = threadIdx.x;
  const int lane = tid & 63;
  const int wave = tid >> 6;
  const int ln15 = lane & 15;
  const int q4   = lane >> 4;
  const int wm   = wave >> 1;
  const int wn   = wave & 1;
  const int m0   = my * 128;
  const int n0   = nx * 128;
  const unsigned short* Ab = A + (size_t)zz * Asb;
  const unsigned short* Bb = B + (size_t)zz * Bsb;

  if (MODE == 1 && tid < 128)
    svb[tid] = sv[(size_t)zz * 2048 + m0 + tid];

  const int srow = lane >> 3;
  const int kcp  = lane & 7;
  const int kcl  = kcp ^ srow;      // xor-swizzled source chunk

  f32x4 acc[4][4] = {};

  for (int k0 = 0; k0 < K; k0 += 64) {
    #pragma unroll
    for (int r = 0; r < 4; r++) {
      int rowg = wave * 32 + r * 8;
      int row  = rowg + srow;
      load_lds16(&Ab[(size_t)(m0 + row) * K + k0 + kcl * 8], &lA[rowg * 64]);
      load_lds16(&Bb[(size_t)(n0 + row) * K + k0 + kcl * 8], &lB[rowg * 64]);
    }
    __syncthreads();
    #pragma unroll
    for (int kk = 0; kk < 2; kk++) {
      bf16x8 af[4], bfr[4];
      #pragma unroll
      for (int mt = 0; mt < 4; mt++) {
        int row = wm * 64 + mt * 16 + ln15;
        int pc  = (kk * 4 + q4) ^ (row & 7);
        af[mt] = *(const bf16x8*)&lA[row * 64 + pc * 8];
      }
      #pragma unroll
      for (int nt = 0; nt < 4; nt++) {
        int row = wn * 64 + nt * 16 + ln15;
        int pc  = (kk * 4 + q4) ^ (row & 7);
        bfr[nt] = *(const bf16x8*)&lB[row * 64 + pc * 8];
      }
      #pragma unroll
      for (int mt = 0; mt < 4; mt++)
        #pragma unroll
        for (int nt = 0; nt < 4; nt++)
          acc[mt][nt] = __builtin_amdgcn_mfma_f32_16x16x32_bf16(
              af[mt], bfr[nt], acc[mt][nt], 0, 0, 0);
    }
    __syncthreads();
  }

  if (MODE == 0) {
    unsigned short* Sb = (unsigned short*)Cout + (size_t)zz * 1024 * 1024;
    #pragma unroll
    for (int mt = 0; mt < 4; mt++) {
      #pragma unroll
      for (int nt = 0; nt < 4; nt++) {
        int col = n0 + wn * 64 + nt * 16 + ln15;
        #pragma unroll
        for (int rg = 0; rg < 4; rg++) {
          int rowi = m0 + wm * 64 + mt * 16 + q4 * 4 + rg;
          Sb[(size_t)rowi * 1024 + col] = (unsigned short)f2bf(acc[mt][nt][rg] * scale);
        }
      }
    }
  } else {
    float* Ob = (float*)Cout;
    #pragma unroll
    for (int mt = 0; mt < 4; mt++) {
      #pragma unroll
      for (int nt = 0; nt < 4; nt++) {
        int l  = n0 + wn * 64 + nt * 16 + ln15;
        int i1 = l >> 5, j1 = l & 31;
        #pragma unroll
        for (int rg = 0; rg < 4; rg++) {
          int rloc = wm * 64 + mt * 16 + q4 * 4 + rg;
          int dp = m0 + rloc;
          int c  = dp & 31;
          int j0 = (dp >> 5) & 7;
          int i0 = dp >> 8;
          int h = i0 * 32 + i1;
          int w = j0 * 32 + j1;
          if (h < 252 && w < 252)
            Ob[(((size_t)zz * 32 + c) * 252 + h) * 252 + w] =
                acc[mt][nt][rg] * svb[rloc];
        }
      }
    }
  }
}

// ---------------------------------------------------------------------------
// Kernel 5: row softmax over S (bf16, in place -> P). Block per row (b,l).
// ---------------------------------------------------------------------------
__global__ void softmax_kernel(unsigned short* __restrict__ S) {
  unsigned short* row = S + (size_t)blockIdx.x * 1024;
  int tid  = threadIdx.x;
  int lane = tid & 63;
  int wid  = tid >> 6;

  uint2 u = *(const uint2*)&row[tid * 4];
  float x0 = bf2f(u.x & 0xFFFF);
  float x1 = bf2f(u.x >> 16);
  float x2 = bf2f(u.y & 0xFFFF);
  float x3 = bf2f(u.y >> 16);

  __shared__ float red[8];
  float mx = fmaxf(fmaxf(x0, x1), fmaxf(x2, x3));
  #pragma unroll
  for (int off = 32; off > 0; off >>= 1) mx = fmaxf(mx, __shfl_down(mx, off));
  if (lane == 0) red[wid] = mx;
  __syncthreads();
  if (tid == 0)
    red[4] = fmaxf(fmaxf(red[0], red[1]), fmaxf(red[2], red[3]));
  __syncthreads();
  float bm = red[4];

  float e0 = __expf(x0 - bm), e1 = __expf(x1 - bm);
  float e2 = __expf(x2 - bm), e3 = __expf(x3 - bm);
  float s = e0 + e1 + e2 + e3;
  #pragma unroll
  for (int off = 32; off > 0; off >>= 1) s += __shfl_down(s, off);
  if (lane == 0) red[wid] = s;
  __syncthreads();
  if (tid == 0) red[5] = 1.0f / (red[0] + red[1] + red[2] + red[3]);
  __syncthreads();
  float inv = red[5];

  unsigned int o0 = f2bf(e0 * inv) | (f2bf(e1 * inv) << 16);
  unsigned int o1 = f2bf(e2 * inv) | (f2bf(e3 * inv) << 16);
  uint2 o; o.x = o0; o.y = o1;
  *(uint2*)&row[tid * 4] = o;
}

// ---------------------------------------------------------------------------
extern "C" void kernel_launch(void* const* d_in, const int* in_sizes, int n_in,
                              void* d_out, int out_size, void* d_ws, size_t ws_size,
                              hipStream_t stream) {
  const float* q = (const float*)d_in[0];
  const float* k = (const float*)d_in[1];
  const float* v = (const float*)d_in[2];
  float* out = (float*)d_out;

  char* ws = (char*)d_ws;
  float* sv = (float*)ws;                                       // 8*2048*4 = 64 KB
  unsigned short* Qh = (unsigned short*)(ws + 196608);          // 32 MB
  unsigned short* Kh = Qh + (size_t)8 * 1024 * 2048;            // 32 MB
  unsigned short* Vt = Kh + (size_t)8 * 1024 * 2048;            // 32 MB
  unsigned short* S  = Vt + (size_t)8 * 2048 * 1024;            // 16 MB

  const float SIM_SCALE = 0.02209708691207961f;  // 2048^-0.5

  pack_qk_fused<<<512, 256, 0, stream>>>(q, k, Qh, Kh);
  pack_v_kernel<<<2048, 256, 0, stream>>>(v, Vt);
  sv_kernel<<<256, 256, 0, stream>>>(Vt, sv);
  gemm_nt<0><<<512, 256, 0, stream>>>(
      Qh, Kh, 2048, 1024 * 2048, 1024 * 2048, (void*)S, SIM_SCALE, nullptr);
  softmax_kernel<<<8192, 256, 0, stream>>>(S);
  gemm_nt<1><<<1024, 256, 0, stream>>>(
      Vt, S, 1024, 2048 * 1024, 1024 * 1024, (void*)out, 1.0f, sv);
}